// Round 2
// baseline (209.151 us; speedup 1.0000x reference)
//
#include <hip/hip_runtime.h>

// log1p thresholds (fp32): ln(6), ln(26), ln(51)
#define THR1 1.7917594909667969f
#define THR2 3.2580966949462891f
#define THR3 3.9318256378173828f
#define W1 0.2f
#define W2 30.0f
#define W3 2500.0f
#define W4 20000.0f

#define BLOCK 256
#define UNROLL 4   // float4-pairs per thread: 8 x 16B loads in flight

__device__ __forceinline__ float bucket_w(float y) {
    return (y < THR1) ? W1 : ((y < THR2) ? W2 : ((y < THR3) ? W3 : W4));
}

__global__ __launch_bounds__(BLOCK) void mae_partial_kernel(
    const float* __restrict__ y_pred,
    const float* __restrict__ y_true,
    float* __restrict__ acc,   // acc[0]=num, acc[1]=den (pre-zeroed)
    int n)
{
    const int n4 = n >> 2;          // number of float4 groups
    const int rem = n & 3;
    const float4* __restrict__ p4 = (const float4*)y_pred;
    const float4* __restrict__ t4 = (const float4*)y_true;

    const int tid  = threadIdx.x;
    const int base = blockIdx.x * (BLOCK * UNROLL) + tid;

    // ---- issue all 2*UNROLL independent 16B loads before any use ----
    float4 a[UNROLL], b[UNROLL];
    bool   v[UNROLL];
    #pragma unroll
    for (int k = 0; k < UNROLL; ++k) {
        const int i = base + k * BLOCK;
        v[k] = (i < n4);
        if (v[k]) { a[k] = p4[i]; b[k] = t4[i]; }
    }

    float num = 0.0f, den = 0.0f;
    #pragma unroll
    for (int k = 0; k < UNROLL; ++k) {
        if (v[k]) {
            float w;
            w = bucket_w(b[k].x); num += w * fabsf(b[k].x - a[k].x); den += w;
            w = bucket_w(b[k].y); num += w * fabsf(b[k].y - a[k].y); den += w;
            w = bucket_w(b[k].z); num += w * fabsf(b[k].z - a[k].z); den += w;
            w = bucket_w(b[k].w); num += w * fabsf(b[k].w - a[k].w); den += w;
        }
    }

    // scalar tail (n % 4 elements) handled by the first `rem` global threads
    const int gtid = blockIdx.x * BLOCK + tid;
    if (gtid < rem) {
        const int j = n4 * 4 + gtid;
        const float aa = y_pred[j];
        const float bb = y_true[j];
        const float w = bucket_w(bb);
        num += w * fabsf(bb - aa);
        den += w;
    }

    // 64-lane wave reduction
    #pragma unroll
    for (int off = 32; off > 0; off >>= 1) {
        num += __shfl_down(num, off, 64);
        den += __shfl_down(den, off, 64);
    }

    // per-block LDS reduction across the 4 waves
    __shared__ float s_num[4];
    __shared__ float s_den[4];
    const int wave = tid >> 6;
    const int lane = tid & 63;
    if (lane == 0) { s_num[wave] = num; s_den[wave] = den; }
    __syncthreads();

    if (tid == 0) {
        const float bn = s_num[0] + s_num[1] + s_num[2] + s_num[3];
        const float bd = s_den[0] + s_den[1] + s_den[2] + s_den[3];
        atomicAdd(&acc[0], bn);
        atomicAdd(&acc[1], bd);
    }
}

__global__ void mae_finalize_kernel(const float* __restrict__ acc,
                                    float* __restrict__ out)
{
    out[0] = acc[0] / acc[1];
}

extern "C" void kernel_launch(void* const* d_in, const int* in_sizes, int n_in,
                              void* d_out, int out_size, void* d_ws, size_t ws_size,
                              hipStream_t stream)
{
    const float* y_pred = (const float*)d_in[0];
    const float* y_true = (const float*)d_in[1];
    float* out = (float*)d_out;
    float* acc = (float*)d_ws;
    const int n = in_sizes[0];

    // d_ws is re-poisoned to 0xAA before every timed launch — zero it each call
    hipMemsetAsync(acc, 0, 2 * sizeof(float), stream);

    const int n4 = n >> 2;
    const int per_block = BLOCK * UNROLL;                 // 1024 float4s per block
    int grid = (n4 + per_block - 1) / per_block;          // 3840 for this problem
    if (grid < 1) grid = 1;

    mae_partial_kernel<<<grid, BLOCK, 0, stream>>>(y_pred, y_true, acc, n);
    mae_finalize_kernel<<<1, 1, 0, stream>>>(acc, out);
}

// Round 3
// 137.410 us; speedup vs baseline: 1.5221x; 1.5221x over previous
//
#include <hip/hip_runtime.h>

// log1p thresholds (fp32): ln(6), ln(26), ln(51)
#define THR1 1.7917594909667969f
#define THR2 3.2580966949462891f
#define THR3 3.9318256378173828f
#define W1 0.2f
#define W2 30.0f
#define W3 2500.0f
#define W4 20000.0f

#define BLOCK 256
#define UNROLL 4                   // float4-pairs per thread per chunk
#define GRID 1280                  // 5 blocks/CU on 256 CUs; 3840 chunks / 1280 = 3 iters exact

__device__ __forceinline__ float bucket_w(float y) {
    return (y < THR1) ? W1 : ((y < THR2) ? W2 : ((y < THR3) ? W3 : W4));
}

__device__ __forceinline__ void accum(float4 a, float4 b, float& num, float& den) {
    float w;
    w = bucket_w(b.x); num += w * fabsf(b.x - a.x); den += w;
    w = bucket_w(b.y); num += w * fabsf(b.y - a.y); den += w;
    w = bucket_w(b.z); num += w * fabsf(b.z - a.z); den += w;
    w = bucket_w(b.w); num += w * fabsf(b.w - a.w); den += w;
}

__global__ __launch_bounds__(BLOCK) void mae_stage1(
    const float* __restrict__ y_pred,
    const float* __restrict__ y_true,
    float2* __restrict__ partials,   // one (num,den) per block
    int n)
{
    const int n4 = n >> 2;
    const int CHUNK = BLOCK * UNROLL;        // 1024 float4s per chunk
    const int nchunks = n4 / CHUNK;          // full chunks (exact for this problem)
    const float4* __restrict__ p4 = (const float4*)y_pred;
    const float4* __restrict__ t4 = (const float4*)y_true;

    float num = 0.0f, den = 0.0f;

    // steady state: NO bounds checks -> 8 independent 16B loads in flight
    for (int c = blockIdx.x; c < nchunks; c += gridDim.x) {
        const int base = c * CHUNK + threadIdx.x;
        const float4 a0 = p4[base + 0 * BLOCK];
        const float4 a1 = p4[base + 1 * BLOCK];
        const float4 a2 = p4[base + 2 * BLOCK];
        const float4 a3 = p4[base + 3 * BLOCK];
        const float4 b0 = t4[base + 0 * BLOCK];
        const float4 b1 = t4[base + 1 * BLOCK];
        const float4 b2 = t4[base + 2 * BLOCK];
        const float4 b3 = t4[base + 3 * BLOCK];
        accum(a0, b0, num, den);
        accum(a1, b1, num, den);
        accum(a2, b2, num, den);
        accum(a3, b3, num, den);
    }

    // tail: any elements beyond the full chunks (zero for this problem shape)
    const int tail_start = nchunks * CHUNK * 4;   // element index
    for (int j = tail_start + blockIdx.x * BLOCK + threadIdx.x; j < n;
         j += gridDim.x * BLOCK) {
        const float aa = y_pred[j];
        const float bb = y_true[j];
        const float w = bucket_w(bb);
        num += w * fabsf(bb - aa);
        den += w;
    }

    // 64-lane wave reduction
    #pragma unroll
    for (int off = 32; off > 0; off >>= 1) {
        num += __shfl_down(num, off, 64);
        den += __shfl_down(den, off, 64);
    }

    __shared__ float s_num[4];
    __shared__ float s_den[4];
    const int wave = threadIdx.x >> 6;
    const int lane = threadIdx.x & 63;
    if (lane == 0) { s_num[wave] = num; s_den[wave] = den; }
    __syncthreads();

    if (threadIdx.x == 0) {
        partials[blockIdx.x] = make_float2(s_num[0] + s_num[1] + s_num[2] + s_num[3],
                                           s_den[0] + s_den[1] + s_den[2] + s_den[3]);
    }
}

__global__ __launch_bounds__(BLOCK) void mae_stage2(
    const float2* __restrict__ partials, int nblocks, float* __restrict__ out)
{
    float num = 0.0f, den = 0.0f;
    for (int i = threadIdx.x; i < nblocks; i += BLOCK) {
        const float2 v = partials[i];
        num += v.x; den += v.y;
    }

    #pragma unroll
    for (int off = 32; off > 0; off >>= 1) {
        num += __shfl_down(num, off, 64);
        den += __shfl_down(den, off, 64);
    }

    __shared__ float s_num[4];
    __shared__ float s_den[4];
    const int wave = threadIdx.x >> 6;
    const int lane = threadIdx.x & 63;
    if (lane == 0) { s_num[wave] = num; s_den[wave] = den; }
    __syncthreads();

    if (threadIdx.x == 0) {
        const float bn = s_num[0] + s_num[1] + s_num[2] + s_num[3];
        const float bd = s_den[0] + s_den[1] + s_den[2] + s_den[3];
        out[0] = bn / bd;
    }
}

extern "C" void kernel_launch(void* const* d_in, const int* in_sizes, int n_in,
                              void* d_out, int out_size, void* d_ws, size_t ws_size,
                              hipStream_t stream)
{
    const float* y_pred = (const float*)d_in[0];
    const float* y_true = (const float*)d_in[1];
    float* out = (float*)d_out;
    float2* partials = (float2*)d_ws;       // GRID float2s, fully overwritten each call
    const int n = in_sizes[0];

    mae_stage1<<<GRID, BLOCK, 0, stream>>>(y_pred, y_true, partials, n);
    mae_stage2<<<1, BLOCK, 0, stream>>>(partials, GRID, out);
}